// Round 4
// baseline (256.448 us; speedup 1.0000x reference)
//
#include <hip/hip_runtime.h>

#define HD 64
#define SLOPE 0.01f
#define BSH 6                    // 64 nodes per bucket
#define BNODES 64
#define CHUNK 4096               // edges per partition block
#define SLOT 1536                // padded edge capacity per bucket (exp max ~1150)
#define TN 32                    // R4: nodes per fused-layer tile (was 64)

// ---------------------------------------------------------------------------
// Build v4 (R13-proven): padded-slot partition -> per-bucket counting sort
// emitting padded CSR. bsort folds the x->fp16 convert in its tail.
// (R2 lesson: direct scatter build = 16x write amplification, 66us. Keep sort.)
// ---------------------------------------------------------------------------

__global__ __launch_bounds__(256) void part_kernel(const int* __restrict__ ei,
                                                   int* __restrict__ bcur,
                                                   int* __restrict__ ebuf,
                                                   int E, int nb) {
    __shared__ int pk_s[CHUNK];
    __shared__ int mt_s[CHUNK];
    __shared__ int hist[784];
    __shared__ int sbase[784];
    const int t = threadIdx.x;
    const int c0 = blockIdx.x * CHUNK;
    const int cnt = min(CHUNK, E - c0);
    for (int i = t; i < nb; i += 256) hist[i] = 0;
    __syncthreads();
    for (int i = t; i < cnt; i += 256) {
        int src = ei[c0 + i];
        int dst = ei[E + c0 + i];
        int b = dst >> BSH;
        pk_s[i] = (src << BSH) | (dst & (BNODES - 1));
        int r = atomicAdd(&hist[b], 1);
        mt_s[i] = (b << 12) | r;           // rank < CHUNK = 2^12
    }
    __syncthreads();
    for (int b = t; b < nb; b += 256) {
        int h = hist[b];
        if (h) sbase[b] = b * SLOT + atomicAdd(&bcur[b], h);   // padded slot
    }
    __syncthreads();
    for (int i = t; i < cnt; i += 256) {
        int m = mt_s[i];
        int b = m >> 12;
        ebuf[sbase[b] + (m & (CHUNK - 1))] = pk_s[i];
    }
}

__global__ __launch_bounds__(256) void bsort_kernel(const int* __restrict__ ebuf,
                                                    const int* __restrict__ bcnt,
                                                    int* __restrict__ colidx,
                                                    int* __restrict__ rowptr,
                                                    int* __restrict__ rowend,
                                                    float* __restrict__ invdeg,
                                                    const float* __restrict__ x,
                                                    _Float16* __restrict__ h16a,
                                                    int n, int n64) {
    __shared__ int cnt[BNODES];
    const int b = blockIdx.x;
    const int t = threadIdx.x;
    const int ebeg = b * SLOT;
    const int eend = ebeg + bcnt[b];
    if (t < BNODES) cnt[t] = 0;
    __syncthreads();
    for (int k = ebeg + t; k < eend; k += 256)
        atomicAdd(&cnt[ebuf[k] & (BNODES - 1)], 1);
    __syncthreads();
    if (t < BNODES) {                      // wave 0: scan the 64 counters
        int v = cnt[t];
        int x2 = v;
        #pragma unroll
        for (int d = 1; d < 64; d <<= 1) { int y = __shfl_up(x2, d, 64); if (t >= d) x2 += y; }
        int excl = x2 - v;
        int node = b * BNODES + t;
        if (node < n) {
            rowptr[node] = ebeg + excl;
            rowend[node] = ebeg + excl + v;
            invdeg[node] = 1.0f / (float)((v > 1) ? v : 1);
        }
        cnt[t] = excl;                     // becomes the running cursor
    }
    __syncthreads();
    for (int k = ebeg + t; k < eend; k += 256) {
        int p = ebuf[k];
        int r = atomicAdd(&cnt[p & (BNODES - 1)], 1);
        colidx[ebeg + r] = p >> BSH;
    }
    // --- folded tohalf: x (f32) -> h16a, grid-stride, 8 elems/iter ---
    const int total8 = n64 >> 3;
    for (int i = b * 256 + t; i < total8; i += gridDim.x * 256) {
        int e = i * 8;
        float4 a = *(const float4*)(x + e);
        float4 c = *(const float4*)(x + e + 4);
        _Float16 o[8] = {(_Float16)a.x, (_Float16)a.y, (_Float16)a.z, (_Float16)a.w,
                         (_Float16)c.x, (_Float16)c.y, (_Float16)c.z, (_Float16)c.w};
        *(float4*)(h16a + e) = *(float4*)o;
    }
}

// ---------------------------------------------------------------------------
// Fused SAGE layer v6 (R4): 32-node tiles. Grid 782->1563 blocks; LDS
// 34.8KB->17.4KB; __launch_bounds__(256,6) -> ~6 blocks/CU = 24 waves/CU
// (was 12). Theory: phase-A random gathers hit L3 latency (~700cy) and 12
// waves/CU can't hide it; 2x occupancy halves exposed latency. Each wave
// handles 8 nodes in ONE pass (one 8-lane group per node). Phase B: 32x64
// GEMM, 2 row-blocks/thread (lower VGPR for the 85-reg budget at 6 w/EU).
// Math identical to R3 (same per-group loop + ci prefetch).
// ---------------------------------------------------------------------------

#define FMA4(acc, am, b0, b1, b2, b3)                                  \
    acc.x += am.x * b0.x + am.y * b1.x + am.z * b2.x + am.w * b3.x;    \
    acc.y += am.x * b0.y + am.y * b1.y + am.z * b2.y + am.w * b3.y;    \
    acc.z += am.x * b0.z + am.y * b1.z + am.z * b2.z + am.w * b3.z;    \
    acc.w += am.x * b0.w + am.y * b1.w + am.z * b2.w + am.w * b3.w;

#define FUSED_BODY(EXTRA_SHARED)                                            \
    __shared__ float sA[TN * 68];     /* mean tile, f32, stride 68 */       \
    __shared__ float sS[TN * 68];     /* self tile, f32 */                  \
    EXTRA_SHARED                                                            \
    const int t = threadIdx.x;                                              \
    const int lane = t & 63;                                                \
    const int w = t >> 6;                                                   \
    const int base = blockIdx.x * TN;                                       \
    const int rows = min(TN, n - base);                                     \
    const float4* __restrict__ g4 = (const float4*)h16_in;                  \
    /* stage self tile from fp16 (4KB streaming read, convert to f32) */    \
    {                                                                       \
        int r = t >> 3, cc = t & 7;       /* 32 rows x 8 chunks = 256 */    \
        float4 raw = {0.f, 0.f, 0.f, 0.f};                                  \
        if (r < rows) raw = g4[(size_t)(base + r) * 8 + cc];                \
        const _Float16* hp = (const _Float16*)&raw;                         \
        float4 lo = {(float)hp[0], (float)hp[1], (float)hp[2], (float)hp[3]}; \
        float4 hi = {(float)hp[4], (float)hp[5], (float)hp[6], (float)hp[7]}; \
        *(float4*)(sS + r * 68 + cc * 8 + 0) = lo;                          \
        *(float4*)(sS + r * 68 + cc * 8 + 4) = hi;                          \
    }                                                                       \
    /* ---- phase A: aggregate into sA (one 8-node pass per wave) ---- */   \
    {                                                                       \
        const int g = lane >> 3;      /* node slot 0..7 */                  \
        const int c8 = lane & 7;      /* 16B chunk of 128B fp16 row */      \
        const int r = w * 8 + g;      /* local row 0..31 */                 \
        const int node = base + r;                                          \
        const bool valid = node < n;                                        \
        int beg = 0, end = 0; float idg = 0.f;                              \
        if (valid) {                                                        \
            beg = rowptr[node];                                             \
            end = rowend[node];                                             \
            idg = invdeg[node];                                             \
        }                                                                   \
        const int deg = end - beg;                                          \
        float4 accA = {0.f, 0.f, 0.f, 0.f};                                 \
        float4 accB = {0.f, 0.f, 0.f, 0.f};                                 \
        int off0 = beg + c8;                                                \
        int ci = (off0 < end) ? colidx[off0] : 0;                           \
        for (int t0 = 0; t0 < deg; t0 += 8) {        /* per-GROUP bound */  \
            const int ci_cur = ci;                                          \
            {   /* prefetch next iteration's chunk */                       \
                int offn = beg + t0 + 8 + c8;                               \
                ci = (offn < end) ? colidx[offn] : 0;                       \
            }                                                               \
            int idx[8];                                                     \
            _Pragma("unroll")                                               \
            for (int k = 0; k < 8; ++k)                                     \
                idx[k] = __shfl(ci_cur, g * 8 + k, 64);                     \
            float4 vv[8];                                                   \
            float sel[8];                                                   \
            _Pragma("unroll")                                               \
            for (int k = 0; k < 8; ++k) {                                   \
                const bool p = (t0 + k) < deg;                              \
                const int safe = p ? idx[k] : 0;                            \
                sel[k] = p ? 1.0f : 0.0f;                                   \
                vv[k] = g4[(size_t)safe * 8 + c8];                          \
            }                                                               \
            _Pragma("unroll")                                               \
            for (int k = 0; k < 8; ++k) {                                   \
                const _Float16* hp = (const _Float16*)&vv[k];               \
                accA.x += sel[k] * (float)hp[0];                            \
                accA.y += sel[k] * (float)hp[1];                            \
                accA.z += sel[k] * (float)hp[2];                            \
                accA.w += sel[k] * (float)hp[3];                            \
                accB.x += sel[k] * (float)hp[4];                            \
                accB.y += sel[k] * (float)hp[5];                            \
                accB.z += sel[k] * (float)hp[6];                            \
                accB.w += sel[k] * (float)hp[7];                            \
            }                                                               \
        }                                                                   \
        float4 oA = {accA.x * idg, accA.y * idg, accA.z * idg, accA.w * idg}; \
        float4 oB = {accB.x * idg, accB.y * idg, accB.z * idg, accB.w * idg}; \
        *(float4*)(sA + r * 68 + c8 * 8 + 0) = oA;                          \
        *(float4*)(sA + r * 68 + c8 * 8 + 4) = oB;                          \
    }                                                                       \
    __syncthreads();                                                        \
    /* ---- phase B: register-blocked GEMM 32x64, W from global ---- */     \
    const int r0 = t & 15;                                                  \
    const int jq = t >> 4;            /* j0/4 */                            \
    const int j0 = jq * 4;                                                  \
    const float4* __restrict__ Wl4 = (const float4*)Wl;                     \
    const float4* __restrict__ Wr4 = (const float4*)Wr;                     \
    const float4 bias = *(const float4*)(bl + j0);                          \
    float4 acc0 = bias, acc1 = bias;                                        \
    _Pragma("unroll 2")                                                     \
    for (int k4 = 0; k4 < 16; ++k4) {                                       \
        float4 b0 = Wl4[(4 * k4 + 0) * 16 + jq];                            \
        float4 b1 = Wl4[(4 * k4 + 1) * 16 + jq];                            \
        float4 b2 = Wl4[(4 * k4 + 2) * 16 + jq];                            \
        float4 b3 = Wl4[(4 * k4 + 3) * 16 + jq];                            \
        float4 a0 = *(const float4*)(sA + (r0 +  0) * 68 + 4 * k4);         \
        float4 a1 = *(const float4*)(sA + (r0 + 16) * 68 + 4 * k4);         \
        FMA4(acc0, a0, b0, b1, b2, b3)                                      \
        FMA4(acc1, a1, b0, b1, b2, b3)                                      \
        b0 = Wr4[(4 * k4 + 0) * 16 + jq];                                   \
        b1 = Wr4[(4 * k4 + 1) * 16 + jq];                                   \
        b2 = Wr4[(4 * k4 + 2) * 16 + jq];                                   \
        b3 = Wr4[(4 * k4 + 3) * 16 + jq];                                   \
        a0 = *(const float4*)(sS + (r0 +  0) * 68 + 4 * k4);                \
        a1 = *(const float4*)(sS + (r0 + 16) * 68 + 4 * k4);                \
        FMA4(acc0, a0, b0, b1, b2, b3)                                      \
        FMA4(acc1, a1, b0, b1, b2, b3)                                      \
    }                                                                       \
    acc0.x = (acc0.x > 0.f) ? acc0.x : SLOPE * acc0.x;                      \
    acc0.y = (acc0.y > 0.f) ? acc0.y : SLOPE * acc0.y;                      \
    acc0.z = (acc0.z > 0.f) ? acc0.z : SLOPE * acc0.z;                      \
    acc0.w = (acc0.w > 0.f) ? acc0.w : SLOPE * acc0.w;                      \
    acc1.x = (acc1.x > 0.f) ? acc1.x : SLOPE * acc1.x;                      \
    acc1.y = (acc1.y > 0.f) ? acc1.y : SLOPE * acc1.y;                      \
    acc1.z = (acc1.z > 0.f) ? acc1.z : SLOPE * acc1.z;                      \
    acc1.w = (acc1.w > 0.f) ? acc1.w : SLOPE * acc1.w;

__global__ __launch_bounds__(256, 6) void sage_fused(
    const _Float16* __restrict__ h16_in, _Float16* __restrict__ h16_out,
    const int* __restrict__ rowptr, const int* __restrict__ rowend,
    const int* __restrict__ colidx, const float* __restrict__ invdeg,
    const float* __restrict__ Wl, const float* __restrict__ bl,
    const float* __restrict__ Wr, int n) {
    FUSED_BODY()
    #define STORE_ROW(S, ACC)                                               \
        { int r = r0 + 16 * S;                                              \
          if (r < rows) {                                                   \
              _Float16 o[4] = {(_Float16)ACC.x, (_Float16)ACC.y,            \
                               (_Float16)ACC.z, (_Float16)ACC.w};           \
              *(float2*)(h16_out + (size_t)(base + r) * HD + j0)            \
                  = *(float2*)o;                                            \
          } }
    STORE_ROW(0, acc0)
    STORE_ROW(1, acc1)
    #undef STORE_ROW
}

// Layer-3 variant: h3 never hits memory — dot with Wout, cross-wave LDS
// reduction, write out[node] (f32) directly.
__global__ __launch_bounds__(256, 6) void sage_fused_out(
    const _Float16* __restrict__ h16_in,
    const int* __restrict__ rowptr, const int* __restrict__ rowend,
    const int* __restrict__ colidx, const float* __restrict__ invdeg,
    const float* __restrict__ Wl, const float* __restrict__ bl,
    const float* __restrict__ Wr,
    const float* __restrict__ Wout, const float* __restrict__ bout,
    float* __restrict__ out, int n) {
    FUSED_BODY(__shared__ float s_part[16][TN];)
    const float4 w4 = *(const float4*)(Wout + j0);
    s_part[jq][r0 +  0] = acc0.x * w4.x + acc0.y * w4.y + acc0.z * w4.z + acc0.w * w4.w;
    s_part[jq][r0 + 16] = acc1.x * w4.x + acc1.y * w4.y + acc1.z * w4.z + acc1.w * w4.w;
    __syncthreads();
    if (t < TN) {
        float sum = 0.f;
        #pragma unroll
        for (int g2 = 0; g2 < 16; ++g2) sum += s_part[g2][t];
        if (t < rows) out[base + t] = sum + bout[0];
    }
}

// ---------------------------------------------------------------------------

extern "C" void kernel_launch(void* const* d_in, const int* in_sizes, int n_in,
                              void* d_out, int out_size, void* d_ws, size_t ws_size,
                              hipStream_t stream) {
    const float* x   = (const float*)d_in[0];
    const int* ei    = (const int*)d_in[1];
    const float* Wl1 = (const float*)d_in[2];
    const float* bl1 = (const float*)d_in[3];
    const float* Wr1 = (const float*)d_in[4];
    const float* Wl2 = (const float*)d_in[5];
    const float* bl2 = (const float*)d_in[6];
    const float* Wr2 = (const float*)d_in[7];
    const float* Wl3 = (const float*)d_in[8];
    const float* bl3 = (const float*)d_in[9];
    const float* Wr3 = (const float*)d_in[10];
    const float* Wout = (const float*)d_in[11];
    const float* bout = (const float*)d_in[12];
    float* out = (float*)d_out;

    const int N = in_sizes[0] / HD;       // 50000
    const int E = in_sizes[1] / 2;        // 800000
    const int NB = (N + BNODES - 1) >> BSH;   // 782 buckets
    const int n64 = N * HD;

    // Workspace layout — float4-accessed buffers first (16B alignment).
    _Float16* h16a = (_Float16*)d_ws;                // [N*64] f16
    _Float16* h16b = h16a + (size_t)N * HD;          // [N*64] f16
    int* ebuf     = (int*)(h16b + (size_t)N * HD);   // [NB*SLOT] packed edges
    int* colidx   = ebuf + (size_t)NB * SLOT;        // [NB*SLOT] padded CSR
    int* rowptr   = colidx + (size_t)NB * SLOT;      // [N]
    int* rowend   = rowptr + N;                      // [N]
    float* invdeg = (float*)(rowend + N);            // [N]
    int* bcur     = (int*)(invdeg + N);              // [784]

    hipMemsetAsync(bcur, 0, 784 * sizeof(int), stream);

    part_kernel<<<(E + CHUNK - 1) / CHUNK, 256, 0, stream>>>(ei, bcur, ebuf, E, NB);
    bsort_kernel<<<NB, 256, 0, stream>>>(ebuf, bcur, colidx, rowptr, rowend,
                                         invdeg, x, h16a, N, n64);

    const int ggrid = (N + TN - 1) / TN;  // 1563 tiles

    sage_fused<<<ggrid, 256, 0, stream>>>(h16a, h16b,
                                          rowptr, rowend, colidx, invdeg,
                                          Wl1, bl1, Wr1, N);
    sage_fused<<<ggrid, 256, 0, stream>>>(h16b, h16a,
                                          rowptr, rowend, colidx, invdeg,
                                          Wl2, bl2, Wr2, N);
    sage_fused_out<<<ggrid, 256, 0, stream>>>(h16a,
                                              rowptr, rowend, colidx, invdeg,
                                              Wl3, bl3, Wr3, Wout, bout, out, N);
}

// Round 6
// 201.463 us; speedup vs baseline: 1.2729x; 1.2729x over previous
//
#include <hip/hip_runtime.h>

#define HD 64
#define SLOPE 0.01f
#define BSH 6                    // 64 nodes per bucket
#define BNODES 64
#define CHUNK 4096               // edges per partition block
#define SLOT 1536                // padded edge capacity per bucket (exp max ~1150)

// ---------------------------------------------------------------------------
// Build v4 (R13-proven): padded-slot partition -> per-bucket counting sort
// emitting padded CSR. bsort folds the x->fp16 convert in its tail.
// (R2 lesson: direct scatter build = 16x write amplification, 66us. Keep sort.)
// (R5 lesson: cooperative-kernel fusion failed correctness — reverted.)
// ---------------------------------------------------------------------------

__global__ __launch_bounds__(256) void part_kernel(const int* __restrict__ ei,
                                                   int* __restrict__ bcur,
                                                   int* __restrict__ ebuf,
                                                   int E, int nb) {
    __shared__ int pk_s[CHUNK];
    __shared__ int mt_s[CHUNK];
    __shared__ int hist[784];
    __shared__ int sbase[784];
    const int t = threadIdx.x;
    const int c0 = blockIdx.x * CHUNK;
    const int cnt = min(CHUNK, E - c0);
    for (int i = t; i < nb; i += 256) hist[i] = 0;
    __syncthreads();
    for (int i = t; i < cnt; i += 256) {
        int src = ei[c0 + i];
        int dst = ei[E + c0 + i];
        int b = dst >> BSH;
        pk_s[i] = (src << BSH) | (dst & (BNODES - 1));
        int r = atomicAdd(&hist[b], 1);
        mt_s[i] = (b << 12) | r;           // rank < CHUNK = 2^12
    }
    __syncthreads();
    for (int b = t; b < nb; b += 256) {
        int h = hist[b];
        if (h) sbase[b] = b * SLOT + atomicAdd(&bcur[b], h);   // padded slot
    }
    __syncthreads();
    for (int i = t; i < cnt; i += 256) {
        int m = mt_s[i];
        int b = m >> 12;
        ebuf[sbase[b] + (m & (CHUNK - 1))] = pk_s[i];
    }
}

__global__ __launch_bounds__(256) void bsort_kernel(const int* __restrict__ ebuf,
                                                    const int* __restrict__ bcnt,
                                                    int* __restrict__ colidx,
                                                    int* __restrict__ rowptr,
                                                    int* __restrict__ rowend,
                                                    float* __restrict__ invdeg,
                                                    const float* __restrict__ x,
                                                    _Float16* __restrict__ h16a,
                                                    int n, int n64) {
    __shared__ int cnt[BNODES];
    const int b = blockIdx.x;
    const int t = threadIdx.x;
    const int ebeg = b * SLOT;
    const int eend = ebeg + bcnt[b];
    if (t < BNODES) cnt[t] = 0;
    __syncthreads();
    for (int k = ebeg + t; k < eend; k += 256)
        atomicAdd(&cnt[ebuf[k] & (BNODES - 1)], 1);
    __syncthreads();
    if (t < BNODES) {                      // wave 0: scan the 64 counters
        int v = cnt[t];
        int x2 = v;
        #pragma unroll
        for (int d = 1; d < 64; d <<= 1) { int y = __shfl_up(x2, d, 64); if (t >= d) x2 += y; }
        int excl = x2 - v;
        int node = b * BNODES + t;
        if (node < n) {
            rowptr[node] = ebeg + excl;
            rowend[node] = ebeg + excl + v;
            invdeg[node] = 1.0f / (float)((v > 1) ? v : 1);
        }
        cnt[t] = excl;                     // becomes the running cursor
    }
    __syncthreads();
    for (int k = ebeg + t; k < eend; k += 256) {
        int p = ebuf[k];
        int r = atomicAdd(&cnt[p & (BNODES - 1)], 1);
        colidx[ebeg + r] = p >> BSH;
    }
    // --- folded tohalf: x (f32) -> h16a, grid-stride, 8 elems/iter ---
    const int total8 = n64 >> 3;
    for (int i = b * 256 + t; i < total8; i += gridDim.x * 256) {
        int e = i * 8;
        float4 a = *(const float4*)(x + e);
        float4 c = *(const float4*)(x + e + 4);
        _Float16 o[8] = {(_Float16)a.x, (_Float16)a.y, (_Float16)a.z, (_Float16)a.w,
                         (_Float16)c.x, (_Float16)c.y, (_Float16)c.z, (_Float16)c.w};
        *(float4*)(h16a + e) = *(float4*)o;
    }
}

// ---------------------------------------------------------------------------
// Fused SAGE layer v7 (R6): R3-verified gather + GEMM, NEW coalesced
// epilogue. R4 counters showed WRITE_SIZE 15.6MB for a 6.4MB output (2.4x
// amplification): the (r0,jq) store pattern scatters 8B chunks across 16
// rows per instruction -> partial-sector writes + L2 RMW fetches. Fix:
// phase-B accs round-trip through sA (dead after phase B), then a fully
// coalesced pass (8 threads = one 128B row) converts f32->fp16 and streams
// 16B/thread. Values bit-identical; only addressing changes.
// ---------------------------------------------------------------------------

#define FMA4(acc, am, b0, b1, b2, b3)                                  \
    acc.x += am.x * b0.x + am.y * b1.x + am.z * b2.x + am.w * b3.x;    \
    acc.y += am.x * b0.y + am.y * b1.y + am.z * b2.y + am.w * b3.y;    \
    acc.z += am.x * b0.z + am.y * b1.z + am.z * b2.z + am.w * b3.z;    \
    acc.w += am.x * b0.w + am.y * b1.w + am.z * b2.w + am.w * b3.w;

#define FUSED_BODY(EXTRA_SHARED)                                            \
    __shared__ float sA[64 * 68];     /* mean tile, f32, stride 68 */       \
    __shared__ float sS[64 * 68];     /* self tile, f32 */                  \
    EXTRA_SHARED                                                            \
    const int t = threadIdx.x;                                              \
    const int lane = t & 63;                                                \
    const int w = t >> 6;                                                   \
    const int base = blockIdx.x * 64;                                       \
    const int rows = min(64, n - base);                                     \
    const float4* __restrict__ g4 = (const float4*)h16_in;                  \
    /* stage self tile from fp16 (8KB streaming read, convert to f32) */    \
    _Pragma("unroll")                                                       \
    for (int idx = 0; idx < 2; ++idx) {                                     \
        int i = t + idx * 256;            /* 0..511 */                      \
        int r = i >> 3, cc = i & 7;                                         \
        float4 raw = {0.f, 0.f, 0.f, 0.f};                                  \
        if (r < rows) raw = g4[(size_t)(base + r) * 8 + cc];                \
        const _Float16* hp = (const _Float16*)&raw;                         \
        float4 lo = {(float)hp[0], (float)hp[1], (float)hp[2], (float)hp[3]}; \
        float4 hi = {(float)hp[4], (float)hp[5], (float)hp[6], (float)hp[7]}; \
        *(float4*)(sS + r * 68 + cc * 8 + 0) = lo;                          \
        *(float4*)(sS + r * 68 + cc * 8 + 4) = hi;                          \
    }                                                                       \
    /* ---- phase A: aggregate into sA ---- */                              \
    {                                                                       \
        const int g = lane >> 3;      /* node slot 0..7 */                  \
        const int c8 = lane & 7;      /* 16B chunk of 128B fp16 row */      \
        _Pragma("unroll")                                                   \
        for (int pass = 0; pass < 2; ++pass) {                              \
            const int r = w * 16 + pass * 8 + g;   /* local row 0..63 */    \
            const int node = base + r;                                      \
            const bool valid = node < n;                                    \
            int beg = 0, end = 0; float idg = 0.f;                          \
            if (valid) {                                                    \
                beg = rowptr[node];                                         \
                end = rowend[node];                                         \
                idg = invdeg[node];                                         \
            }                                                               \
            const int deg = end - beg;                                      \
            float4 accA = {0.f, 0.f, 0.f, 0.f};                             \
            float4 accB = {0.f, 0.f, 0.f, 0.f};                             \
            /* prefetch first colidx chunk */                               \
            int off0 = beg + c8;                                            \
            int ci = (off0 < end) ? colidx[off0] : 0;                       \
            for (int t0 = 0; t0 < deg; t0 += 8) {    /* per-GROUP bound */  \
                const int ci_cur = ci;                                      \
                {   /* prefetch next iteration's chunk */                   \
                    int offn = beg + t0 + 8 + c8;                           \
                    ci = (offn < end) ? colidx[offn] : 0;                   \
                }                                                           \
                int idx[8];                                                 \
                _Pragma("unroll")                                           \
                for (int k = 0; k < 8; ++k)                                 \
                    idx[k] = __shfl(ci_cur, g * 8 + k, 64);                 \
                float4 vv[8];                                               \
                float sel[8];                                               \
                _Pragma("unroll")                                           \
                for (int k = 0; k < 8; ++k) {                               \
                    const bool p = (t0 + k) < deg;                          \
                    const int safe = p ? idx[k] : 0;                        \
                    sel[k] = p ? 1.0f : 0.0f;                               \
                    vv[k] = g4[(size_t)safe * 8 + c8];                      \
                }                                                           \
                _Pragma("unroll")                                           \
                for (int k = 0; k < 8; ++k) {                               \
                    const _Float16* hp = (const _Float16*)&vv[k];           \
                    accA.x += sel[k] * (float)hp[0];                        \
                    accA.y += sel[k] * (float)hp[1];                        \
                    accA.z += sel[k] * (float)hp[2];                        \
                    accA.w += sel[k] * (float)hp[3];                        \
                    accB.x += sel[k] * (float)hp[4];                        \
                    accB.y += sel[k] * (float)hp[5];                        \
                    accB.z += sel[k] * (float)hp[6];                        \
                    accB.w += sel[k] * (float)hp[7];                        \
                }                                                           \
            }                                                               \
            float4 oA = {accA.x * idg, accA.y * idg, accA.z * idg, accA.w * idg}; \
            float4 oB = {accB.x * idg, accB.y * idg, accB.z * idg, accB.w * idg}; \
            *(float4*)(sA + r * 68 + c8 * 8 + 0) = oA;                      \
            *(float4*)(sA + r * 68 + c8 * 8 + 4) = oB;                      \
        }                                                                   \
    }                                                                       \
    __syncthreads();                                                        \
    /* ---- phase B: register-blocked GEMM, W from global (L1-hot) ---- */  \
    const int r0 = t & 15;                                                  \
    const int jq = t >> 4;            /* j0/4 */                            \
    const int j0 = jq * 4;                                                  \
    const float4* __restrict__ Wl4 = (const float4*)Wl;                     \
    const float4* __restrict__ Wr4 = (const float4*)Wr;                     \
    const float4 bias = *(const float4*)(bl + j0);                          \
    float4 acc0 = bias, acc1 = bias, acc2 = bias, acc3 = bias;              \
    _Pragma("unroll 2")                                                     \
    for (int k4 = 0; k4 < 16; ++k4) {                                       \
        float4 b0 = Wl4[(4 * k4 + 0) * 16 + jq];                            \
        float4 b1 = Wl4[(4 * k4 + 1) * 16 + jq];                            \
        float4 b2 = Wl4[(4 * k4 + 2) * 16 + jq];                            \
        float4 b3 = Wl4[(4 * k4 + 3) * 16 + jq];                            \
        float4 a0 = *(const float4*)(sA + (r0 +  0) * 68 + 4 * k4);         \
        float4 a1 = *(const float4*)(sA + (r0 + 16) * 68 + 4 * k4);         \
        float4 a2 = *(const float4*)(sA + (r0 + 32) * 68 + 4 * k4);         \
        float4 a3 = *(const float4*)(sA + (r0 + 48) * 68 + 4 * k4);         \
        FMA4(acc0, a0, b0, b1, b2, b3)                                      \
        FMA4(acc1, a1, b0, b1, b2, b3)                                      \
        FMA4(acc2, a2, b0, b1, b2, b3)                                      \
        FMA4(acc3, a3, b0, b1, b2, b3)                                      \
        b0 = Wr4[(4 * k4 + 0) * 16 + jq];                                   \
        b1 = Wr4[(4 * k4 + 1) * 16 + jq];                                   \
        b2 = Wr4[(4 * k4 + 2) * 16 + jq];                                   \
        b3 = Wr4[(4 * k4 + 3) * 16 + jq];                                   \
        a0 = *(const float4*)(sS + (r0 +  0) * 68 + 4 * k4);                \
        a1 = *(const float4*)(sS + (r0 + 16) * 68 + 4 * k4);                \
        a2 = *(const float4*)(sS + (r0 + 32) * 68 + 4 * k4);                \
        a3 = *(const float4*)(sS + (r0 + 48) * 68 + 4 * k4);                \
        FMA4(acc0, a0, b0, b1, b2, b3)                                      \
        FMA4(acc1, a1, b0, b1, b2, b3)                                      \
        FMA4(acc2, a2, b0, b1, b2, b3)                                      \
        FMA4(acc3, a3, b0, b1, b2, b3)                                      \
    }                                                                       \
    acc0.x = (acc0.x > 0.f) ? acc0.x : SLOPE * acc0.x;                      \
    acc0.y = (acc0.y > 0.f) ? acc0.y : SLOPE * acc0.y;                      \
    acc0.z = (acc0.z > 0.f) ? acc0.z : SLOPE * acc0.z;                      \
    acc0.w = (acc0.w > 0.f) ? acc0.w : SLOPE * acc0.w;                      \
    acc1.x = (acc1.x > 0.f) ? acc1.x : SLOPE * acc1.x;                      \
    acc1.y = (acc1.y > 0.f) ? acc1.y : SLOPE * acc1.y;                      \
    acc1.z = (acc1.z > 0.f) ? acc1.z : SLOPE * acc1.z;                      \
    acc1.w = (acc1.w > 0.f) ? acc1.w : SLOPE * acc1.w;                      \
    acc2.x = (acc2.x > 0.f) ? acc2.x : SLOPE * acc2.x;                      \
    acc2.y = (acc2.y > 0.f) ? acc2.y : SLOPE * acc2.y;                      \
    acc2.z = (acc2.z > 0.f) ? acc2.z : SLOPE * acc2.z;                      \
    acc2.w = (acc2.w > 0.f) ? acc2.w : SLOPE * acc2.w;                      \
    acc3.x = (acc3.x > 0.f) ? acc3.x : SLOPE * acc3.x;                      \
    acc3.y = (acc3.y > 0.f) ? acc3.y : SLOPE * acc3.y;                      \
    acc3.z = (acc3.z > 0.f) ? acc3.z : SLOPE * acc3.z;                      \
    acc3.w = (acc3.w > 0.f) ? acc3.w : SLOPE * acc3.w;

__global__ __launch_bounds__(256, 4) void sage_fused(
    const _Float16* __restrict__ h16_in, _Float16* __restrict__ h16_out,
    const int* __restrict__ rowptr, const int* __restrict__ rowend,
    const int* __restrict__ colidx, const float* __restrict__ invdeg,
    const float* __restrict__ Wl, const float* __restrict__ bl,
    const float* __restrict__ Wr, int n) {
    FUSED_BODY()
    // ---- coalesced epilogue: accs -> sA (dead) -> fp16 global ----
    __syncthreads();            // all phase-B sA reads done before overwrite
    *(float4*)(sA + (r0 +  0) * 68 + j0) = acc0;
    *(float4*)(sA + (r0 + 16) * 68 + j0) = acc1;
    *(float4*)(sA + (r0 + 32) * 68 + j0) = acc2;
    *(float4*)(sA + (r0 + 48) * 68 + j0) = acc3;
    __syncthreads();
    #pragma unroll
    for (int idx = 0; idx < 2; ++idx) {
        int i = t + idx * 256;            // 0..511
        int r = i >> 3, cc = i & 7;       // 8 threads cover one 128B row
        if (r < rows) {
            float4 lo = *(const float4*)(sA + r * 68 + cc * 8 + 0);
            float4 hi = *(const float4*)(sA + r * 68 + cc * 8 + 4);
            _Float16 o[8] = {(_Float16)lo.x, (_Float16)lo.y,
                             (_Float16)lo.z, (_Float16)lo.w,
                             (_Float16)hi.x, (_Float16)hi.y,
                             (_Float16)hi.z, (_Float16)hi.w};
            *(float4*)(h16_out + (size_t)(base + r) * HD + cc * 8) = *(float4*)o;
        }
    }
}

// Layer-3 variant: h3 never hits memory — dot with Wout, cross-wave LDS
// reduction, write out[node] (f32) directly.
__global__ __launch_bounds__(256, 4) void sage_fused_out(
    const _Float16* __restrict__ h16_in,
    const int* __restrict__ rowptr, const int* __restrict__ rowend,
    const int* __restrict__ colidx, const float* __restrict__ invdeg,
    const float* __restrict__ Wl, const float* __restrict__ bl,
    const float* __restrict__ Wr,
    const float* __restrict__ Wout, const float* __restrict__ bout,
    float* __restrict__ out, int n) {
    FUSED_BODY(__shared__ float s_part[16][64];)
    const float4 w4 = *(const float4*)(Wout + j0);
    s_part[jq][r0 +  0] = acc0.x * w4.x + acc0.y * w4.y + acc0.z * w4.z + acc0.w * w4.w;
    s_part[jq][r0 + 16] = acc1.x * w4.x + acc1.y * w4.y + acc1.z * w4.z + acc1.w * w4.w;
    s_part[jq][r0 + 32] = acc2.x * w4.x + acc2.y * w4.y + acc2.z * w4.z + acc2.w * w4.w;
    s_part[jq][r0 + 48] = acc3.x * w4.x + acc3.y * w4.y + acc3.z * w4.z + acc3.w * w4.w;
    __syncthreads();
    if (t < 64) {
        float sum = 0.f;
        #pragma unroll
        for (int g2 = 0; g2 < 16; ++g2) sum += s_part[g2][t];
        if (t < rows) out[base + t] = sum + bout[0];
    }
}

// ---------------------------------------------------------------------------

extern "C" void kernel_launch(void* const* d_in, const int* in_sizes, int n_in,
                              void* d_out, int out_size, void* d_ws, size_t ws_size,
                              hipStream_t stream) {
    const float* x   = (const float*)d_in[0];
    const int* ei    = (const int*)d_in[1];
    const float* Wl1 = (const float*)d_in[2];
    const float* bl1 = (const float*)d_in[3];
    const float* Wr1 = (const float*)d_in[4];
    const float* Wl2 = (const float*)d_in[5];
    const float* bl2 = (const float*)d_in[6];
    const float* Wr2 = (const float*)d_in[7];
    const float* Wl3 = (const float*)d_in[8];
    const float* bl3 = (const float*)d_in[9];
    const float* Wr3 = (const float*)d_in[10];
    const float* Wout = (const float*)d_in[11];
    const float* bout = (const float*)d_in[12];
    float* out = (float*)d_out;

    const int N = in_sizes[0] / HD;       // 50000
    const int E = in_sizes[1] / 2;        // 800000
    const int NB = (N + BNODES - 1) >> BSH;   // 782 buckets
    const int n64 = N * HD;

    // Workspace layout — float4-accessed buffers first (16B alignment).
    _Float16* h16a = (_Float16*)d_ws;                // [N*64] f16
    _Float16* h16b = h16a + (size_t)N * HD;          // [N*64] f16
    int* ebuf     = (int*)(h16b + (size_t)N * HD);   // [NB*SLOT] packed edges
    int* colidx   = ebuf + (size_t)NB * SLOT;        // [NB*SLOT] padded CSR
    int* rowptr   = colidx + (size_t)NB * SLOT;      // [N]
    int* rowend   = rowptr + N;                      // [N]
    float* invdeg = (float*)(rowend + N);            // [N]
    int* bcur     = (int*)(invdeg + N);              // [784]

    hipMemsetAsync(bcur, 0, 784 * sizeof(int), stream);

    part_kernel<<<(E + CHUNK - 1) / CHUNK, 256, 0, stream>>>(ei, bcur, ebuf, E, NB);
    bsort_kernel<<<NB, 256, 0, stream>>>(ebuf, bcur, colidx, rowptr, rowend,
                                         invdeg, x, h16a, N, n64);

    const int ggrid = (N + 63) / 64;      // 782 tiles

    sage_fused<<<ggrid, 256, 0, stream>>>(h16a, h16b,
                                          rowptr, rowend, colidx, invdeg,
                                          Wl1, bl1, Wr1, N);
    sage_fused<<<ggrid, 256, 0, stream>>>(h16b, h16a,
                                          rowptr, rowend, colidx, invdeg,
                                          Wl2, bl2, Wr2, N);
    sage_fused_out<<<ggrid, 256, 0, stream>>>(h16a,
                                              rowptr, rowend, colidx, invdeg,
                                              Wl3, bl3, Wr3, Wout, bout, out, N);
}

// Round 7
// 201.381 us; speedup vs baseline: 1.2734x; 1.0004x over previous
//
#include <hip/hip_runtime.h>

#define HD 64
#define SLOPE 0.01f
#define BSH 6                    // 64 nodes per bucket
#define BNODES 64
#define CHUNK 4096               // edges per partition block
#define SLOT 1536                // padded edge capacity per bucket (exp max ~1150)
#define SIDX 1280                // LDS-staged colidx capacity (5KB)

// ---------------------------------------------------------------------------
// Build v4 (R13-proven): padded-slot partition -> per-bucket counting sort
// emitting padded CSR. bsort folds the x->fp16 convert in its tail.
// (R2 lesson: direct scatter build = 16x write amplification. Keep sort.)
// (R5 lesson: cooperative-kernel fusion failed correctness — reverted.)
// ---------------------------------------------------------------------------

__global__ __launch_bounds__(256) void part_kernel(const int* __restrict__ ei,
                                                   int* __restrict__ bcur,
                                                   int* __restrict__ ebuf,
                                                   int E, int nb) {
    __shared__ int pk_s[CHUNK];
    __shared__ int mt_s[CHUNK];
    __shared__ int hist[784];
    __shared__ int sbase[784];
    const int t = threadIdx.x;
    const int c0 = blockIdx.x * CHUNK;
    const int cnt = min(CHUNK, E - c0);
    for (int i = t; i < nb; i += 256) hist[i] = 0;
    __syncthreads();
    for (int i = t; i < cnt; i += 256) {
        int src = ei[c0 + i];
        int dst = ei[E + c0 + i];
        int b = dst >> BSH;
        pk_s[i] = (src << BSH) | (dst & (BNODES - 1));
        int r = atomicAdd(&hist[b], 1);
        mt_s[i] = (b << 12) | r;           // rank < CHUNK = 2^12
    }
    __syncthreads();
    for (int b = t; b < nb; b += 256) {
        int h = hist[b];
        if (h) sbase[b] = b * SLOT + atomicAdd(&bcur[b], h);   // padded slot
    }
    __syncthreads();
    for (int i = t; i < cnt; i += 256) {
        int m = mt_s[i];
        int b = m >> 12;
        ebuf[sbase[b] + (m & (CHUNK - 1))] = pk_s[i];
    }
}

__global__ __launch_bounds__(256) void bsort_kernel(const int* __restrict__ ebuf,
                                                    const int* __restrict__ bcnt,
                                                    int* __restrict__ colidx,
                                                    int* __restrict__ rowptr,
                                                    int* __restrict__ rowend,
                                                    float* __restrict__ invdeg,
                                                    const float* __restrict__ x,
                                                    _Float16* __restrict__ h16a,
                                                    int n, int n64) {
    __shared__ int cnt[BNODES];
    const int b = blockIdx.x;
    const int t = threadIdx.x;
    const int ebeg = b * SLOT;
    const int eend = ebeg + bcnt[b];
    if (t < BNODES) cnt[t] = 0;
    __syncthreads();
    for (int k = ebeg + t; k < eend; k += 256)
        atomicAdd(&cnt[ebuf[k] & (BNODES - 1)], 1);
    __syncthreads();
    if (t < BNODES) {                      // wave 0: scan the 64 counters
        int v = cnt[t];
        int x2 = v;
        #pragma unroll
        for (int d = 1; d < 64; d <<= 1) { int y = __shfl_up(x2, d, 64); if (t >= d) x2 += y; }
        int excl = x2 - v;
        int node = b * BNODES + t;
        if (node < n) {
            rowptr[node] = ebeg + excl;
            rowend[node] = ebeg + excl + v;
            invdeg[node] = 1.0f / (float)((v > 1) ? v : 1);
        }
        cnt[t] = excl;                     // becomes the running cursor
    }
    __syncthreads();
    for (int k = ebeg + t; k < eend; k += 256) {
        int p = ebuf[k];
        int r = atomicAdd(&cnt[p & (BNODES - 1)], 1);
        colidx[ebeg + r] = p >> BSH;
    }
    // --- folded tohalf: x (f32) -> h16a, grid-stride, 8 elems/iter ---
    const int total8 = n64 >> 3;
    for (int i = b * 256 + t; i < total8; i += gridDim.x * 256) {
        int e = i * 8;
        float4 a = *(const float4*)(x + e);
        float4 c = *(const float4*)(x + e + 4);
        _Float16 o[8] = {(_Float16)a.x, (_Float16)a.y, (_Float16)a.z, (_Float16)a.w,
                         (_Float16)c.x, (_Float16)c.y, (_Float16)c.z, (_Float16)c.w};
        *(float4*)(h16a + e) = *(float4*)o;
    }
}

// ---------------------------------------------------------------------------
// Fused SAGE layer v8 (R7): LDS-staged colidx. The block's CSR window is
// contiguous (bucket == 64-node tile), so stage colidx[blk*SLOT..+cnt) into
// LDS once (coalesced), then each 8-lane group reads its 8 indices as LDS
// BROADCASTS. Removes: per-iter global colidx load, the ci prefetch, and
// ALL 8 ds_bpermute shfls per iteration — the feature gathers become the
// only global loads in the loop and pipeline freely. Per-group deg loop is
// now shfl-free => group divergence fully safe. Block-uniform fallback to
// global indices if bucket count > SIDX (never expected).
// R4/R6 counters: layer = 22% VALU, 0 MFMA, 12% HBM — memory-latency-chain
// bound. Epilogue: R6 coalesced store (kept).
// ---------------------------------------------------------------------------

#define FMA4(acc, am, b0, b1, b2, b3)                                  \
    acc.x += am.x * b0.x + am.y * b1.x + am.z * b2.x + am.w * b3.x;    \
    acc.y += am.x * b0.y + am.y * b1.y + am.z * b2.y + am.w * b3.y;    \
    acc.z += am.x * b0.z + am.y * b1.z + am.z * b2.z + am.w * b3.z;    \
    acc.w += am.x * b0.w + am.y * b1.w + am.z * b2.w + am.w * b3.w;

#define GATHER_LOOP(IDX_EXPR)                                               \
    for (int t0 = 0; t0 < deg; t0 += 8) {                                   \
        float4 vv[8];                                                       \
        float sel[8];                                                       \
        _Pragma("unroll")                                                   \
        for (int k = 0; k < 8; ++k) {                                       \
            const int li = beg_l + t0 + k;                                  \
            const int cix = IDX_EXPR;                                       \
            const bool p = (t0 + k) < deg;                                  \
            sel[k] = p ? 1.0f : 0.0f;                                       \
            const int safe = p ? cix : 0;                                   \
            vv[k] = g4[(size_t)safe * 8 + c8];                              \
        }                                                                   \
        _Pragma("unroll")                                                   \
        for (int k = 0; k < 8; ++k) {                                       \
            const _Float16* hp = (const _Float16*)&vv[k];                   \
            accA.x += sel[k] * (float)hp[0];                                \
            accA.y += sel[k] * (float)hp[1];                                \
            accA.z += sel[k] * (float)hp[2];                                \
            accA.w += sel[k] * (float)hp[3];                                \
            accB.x += sel[k] * (float)hp[4];                                \
            accB.y += sel[k] * (float)hp[5];                                \
            accB.z += sel[k] * (float)hp[6];                                \
            accB.w += sel[k] * (float)hp[7];                                \
        }                                                                   \
    }

#define FUSED_BODY(EXTRA_SHARED)                                            \
    __shared__ float sA[64 * 68];     /* mean tile, f32, stride 68 */       \
    __shared__ float sS[64 * 68];     /* self tile, f32 */                  \
    __shared__ int sidx[SIDX];        /* staged colidx window, 5KB */       \
    EXTRA_SHARED                                                            \
    const int t = threadIdx.x;                                              \
    const int lane = t & 63;                                                \
    const int w = t >> 6;                                                   \
    const int base = blockIdx.x * 64;                                       \
    const int rows = min(64, n - base);                                     \
    const int ebeg = blockIdx.x * SLOT;                                     \
    const float4* __restrict__ g4 = (const float4*)h16_in;                  \
    /* stage this block's colidx window into LDS (coalesced) */             \
    const int cnt_e = rowend[base + rows - 1] - ebeg;                       \
    {                                                                       \
        const int cnt_s = min(cnt_e, SIDX);                                 \
        for (int i = t; i < cnt_s; i += 256) sidx[i] = colidx[ebeg + i];    \
    }                                                                       \
    /* stage self tile from fp16 (8KB streaming read, convert to f32) */    \
    _Pragma("unroll")                                                       \
    for (int idx = 0; idx < 2; ++idx) {                                     \
        int i = t + idx * 256;            /* 0..511 */                      \
        int r = i >> 3, cc = i & 7;                                         \
        float4 raw = {0.f, 0.f, 0.f, 0.f};                                  \
        if (r < rows) raw = g4[(size_t)(base + r) * 8 + cc];                \
        const _Float16* hp = (const _Float16*)&raw;                         \
        float4 lo = {(float)hp[0], (float)hp[1], (float)hp[2], (float)hp[3]}; \
        float4 hi = {(float)hp[4], (float)hp[5], (float)hp[6], (float)hp[7]}; \
        *(float4*)(sS + r * 68 + cc * 8 + 0) = lo;                          \
        *(float4*)(sS + r * 68 + cc * 8 + 4) = hi;                          \
    }                                                                       \
    __syncthreads();                  /* sidx ready for phase A */          \
    /* ---- phase A: aggregate into sA ---- */                              \
    {                                                                       \
        const int g = lane >> 3;      /* node slot 0..7 */                  \
        const int c8 = lane & 7;      /* 16B chunk of 128B fp16 row */      \
        _Pragma("unroll")                                                   \
        for (int pass = 0; pass < 2; ++pass) {                              \
            const int r = w * 16 + pass * 8 + g;   /* local row 0..63 */    \
            const int node = base + r;                                      \
            const bool valid = node < n;                                    \
            int beg = 0, end = 0; float idg = 0.f;                          \
            if (valid) {                                                    \
                beg = rowptr[node];                                         \
                end = rowend[node];                                         \
                idg = invdeg[node];                                         \
            }                                                               \
            const int deg = end - beg;                                      \
            const int beg_l = beg - ebeg;                                   \
            float4 accA = {0.f, 0.f, 0.f, 0.f};                             \
            float4 accB = {0.f, 0.f, 0.f, 0.f};                             \
            if (cnt_e <= SIDX) {                                            \
                GATHER_LOOP(sidx[li])                                       \
            } else {                                                        \
                GATHER_LOOP(colidx[ebeg + li])                              \
            }                                                               \
            float4 oA = {accA.x * idg, accA.y * idg, accA.z * idg, accA.w * idg}; \
            float4 oB = {accB.x * idg, accB.y * idg, accB.z * idg, accB.w * idg}; \
            *(float4*)(sA + r * 68 + c8 * 8 + 0) = oA;                      \
            *(float4*)(sA + r * 68 + c8 * 8 + 4) = oB;                      \
        }                                                                   \
    }                                                                       \
    __syncthreads();                                                        \
    /* ---- phase B: register-blocked GEMM, W from global (L1-hot) ---- */  \
    const int r0 = t & 15;                                                  \
    const int jq = t >> 4;            /* j0/4 */                            \
    const int j0 = jq * 4;                                                  \
    const float4* __restrict__ Wl4 = (const float4*)Wl;                     \
    const float4* __restrict__ Wr4 = (const float4*)Wr;                     \
    const float4 bias = *(const float4*)(bl + j0);                          \
    float4 acc0 = bias, acc1 = bias, acc2 = bias, acc3 = bias;              \
    _Pragma("unroll 2")                                                     \
    for (int k4 = 0; k4 < 16; ++k4) {                                       \
        float4 b0 = Wl4[(4 * k4 + 0) * 16 + jq];                            \
        float4 b1 = Wl4[(4 * k4 + 1) * 16 + jq];                            \
        float4 b2 = Wl4[(4 * k4 + 2) * 16 + jq];                            \
        float4 b3 = Wl4[(4 * k4 + 3) * 16 + jq];                            \
        float4 a0 = *(const float4*)(sA + (r0 +  0) * 68 + 4 * k4);         \
        float4 a1 = *(const float4*)(sA + (r0 + 16) * 68 + 4 * k4);         \
        float4 a2 = *(const float4*)(sA + (r0 + 32) * 68 + 4 * k4);         \
        float4 a3 = *(const float4*)(sA + (r0 + 48) * 68 + 4 * k4);         \
        FMA4(acc0, a0, b0, b1, b2, b3)                                      \
        FMA4(acc1, a1, b0, b1, b2, b3)                                      \
        FMA4(acc2, a2, b0, b1, b2, b3)                                      \
        FMA4(acc3, a3, b0, b1, b2, b3)                                      \
        b0 = Wr4[(4 * k4 + 0) * 16 + jq];                                   \
        b1 = Wr4[(4 * k4 + 1) * 16 + jq];                                   \
        b2 = Wr4[(4 * k4 + 2) * 16 + jq];                                   \
        b3 = Wr4[(4 * k4 + 3) * 16 + jq];                                   \
        a0 = *(const float4*)(sS + (r0 +  0) * 68 + 4 * k4);                \
        a1 = *(const float4*)(sS + (r0 + 16) * 68 + 4 * k4);                \
        a2 = *(const float4*)(sS + (r0 + 32) * 68 + 4 * k4);                \
        a3 = *(const float4*)(sS + (r0 + 48) * 68 + 4 * k4);                \
        FMA4(acc0, a0, b0, b1, b2, b3)                                      \
        FMA4(acc1, a1, b0, b1, b2, b3)                                      \
        FMA4(acc2, a2, b0, b1, b2, b3)                                      \
        FMA4(acc3, a3, b0, b1, b2, b3)                                      \
    }                                                                       \
    acc0.x = (acc0.x > 0.f) ? acc0.x : SLOPE * acc0.x;                      \
    acc0.y = (acc0.y > 0.f) ? acc0.y : SLOPE * acc0.y;                      \
    acc0.z = (acc0.z > 0.f) ? acc0.z : SLOPE * acc0.z;                      \
    acc0.w = (acc0.w > 0.f) ? acc0.w : SLOPE * acc0.w;                      \
    acc1.x = (acc1.x > 0.f) ? acc1.x : SLOPE * acc1.x;                      \
    acc1.y = (acc1.y > 0.f) ? acc1.y : SLOPE * acc1.y;                      \
    acc1.z = (acc1.z > 0.f) ? acc1.z : SLOPE * acc1.z;                      \
    acc1.w = (acc1.w > 0.f) ? acc1.w : SLOPE * acc1.w;                      \
    acc2.x = (acc2.x > 0.f) ? acc2.x : SLOPE * acc2.x;                      \
    acc2.y = (acc2.y > 0.f) ? acc2.y : SLOPE * acc2.y;                      \
    acc2.z = (acc2.z > 0.f) ? acc2.z : SLOPE * acc2.z;                      \
    acc2.w = (acc2.w > 0.f) ? acc2.w : SLOPE * acc2.w;                      \
    acc3.x = (acc3.x > 0.f) ? acc3.x : SLOPE * acc3.x;                      \
    acc3.y = (acc3.y > 0.f) ? acc3.y : SLOPE * acc3.y;                      \
    acc3.z = (acc3.z > 0.f) ? acc3.z : SLOPE * acc3.z;                      \
    acc3.w = (acc3.w > 0.f) ? acc3.w : SLOPE * acc3.w;

__global__ __launch_bounds__(256, 4) void sage_fused(
    const _Float16* __restrict__ h16_in, _Float16* __restrict__ h16_out,
    const int* __restrict__ rowptr, const int* __restrict__ rowend,
    const int* __restrict__ colidx, const float* __restrict__ invdeg,
    const float* __restrict__ Wl, const float* __restrict__ bl,
    const float* __restrict__ Wr, int n) {
    FUSED_BODY()
    // ---- coalesced epilogue: accs -> sA (dead) -> fp16 global ----
    __syncthreads();            // all phase-B sA reads done before overwrite
    *(float4*)(sA + (r0 +  0) * 68 + j0) = acc0;
    *(float4*)(sA + (r0 + 16) * 68 + j0) = acc1;
    *(float4*)(sA + (r0 + 32) * 68 + j0) = acc2;
    *(float4*)(sA + (r0 + 48) * 68 + j0) = acc3;
    __syncthreads();
    #pragma unroll
    for (int idx = 0; idx < 2; ++idx) {
        int i = t + idx * 256;            // 0..511
        int r = i >> 3, cc = i & 7;       // 8 threads cover one 128B row
        if (r < rows) {
            float4 lo = *(const float4*)(sA + r * 68 + cc * 8 + 0);
            float4 hi = *(const float4*)(sA + r * 68 + cc * 8 + 4);
            _Float16 o[8] = {(_Float16)lo.x, (_Float16)lo.y,
                             (_Float16)lo.z, (_Float16)lo.w,
                             (_Float16)hi.x, (_Float16)hi.y,
                             (_Float16)hi.z, (_Float16)hi.w};
            *(float4*)(h16_out + (size_t)(base + r) * HD + cc * 8) = *(float4*)o;
        }
    }
}

// Layer-3 variant: h3 never hits memory — dot with Wout, cross-wave LDS
// reduction, write out[node] (f32) directly. s_part aliases the dead sidx
// (5KB >= 4KB needed; sidx unused after phase A, barrier intervenes).
__global__ __launch_bounds__(256, 4) void sage_fused_out(
    const _Float16* __restrict__ h16_in,
    const int* __restrict__ rowptr, const int* __restrict__ rowend,
    const int* __restrict__ colidx, const float* __restrict__ invdeg,
    const float* __restrict__ Wl, const float* __restrict__ bl,
    const float* __restrict__ Wr,
    const float* __restrict__ Wout, const float* __restrict__ bout,
    float* __restrict__ out, int n) {
    FUSED_BODY()
    float* s_part = (float*)sidx;     // [16][64] alias, sidx dead here
    const float4 w4 = *(const float4*)(Wout + j0);
    s_part[jq * 64 + r0 +  0] = acc0.x * w4.x + acc0.y * w4.y + acc0.z * w4.z + acc0.w * w4.w;
    s_part[jq * 64 + r0 + 16] = acc1.x * w4.x + acc1.y * w4.y + acc1.z * w4.z + acc1.w * w4.w;
    s_part[jq * 64 + r0 + 32] = acc2.x * w4.x + acc2.y * w4.y + acc2.z * w4.z + acc2.w * w4.w;
    s_part[jq * 64 + r0 + 48] = acc3.x * w4.x + acc3.y * w4.y + acc3.z * w4.z + acc3.w * w4.w;
    __syncthreads();
    if (t < 64) {
        float sum = 0.f;
        #pragma unroll
        for (int g2 = 0; g2 < 16; ++g2) sum += s_part[g2 * 64 + t];
        if (t < rows) out[base + t] = sum + bout[0];
    }
}

// ---------------------------------------------------------------------------

extern "C" void kernel_launch(void* const* d_in, const int* in_sizes, int n_in,
                              void* d_out, int out_size, void* d_ws, size_t ws_size,
                              hipStream_t stream) {
    const float* x   = (const float*)d_in[0];
    const int* ei    = (const int*)d_in[1];
    const float* Wl1 = (const float*)d_in[2];
    const float* bl1 = (const float*)d_in[3];
    const float* Wr1 = (const float*)d_in[4];
    const float* Wl2 = (const float*)d_in[5];
    const float* bl2 = (const float*)d_in[6];
    const float* Wr2 = (const float*)d_in[7];
    const float* Wl3 = (const float*)d_in[8];
    const float* bl3 = (const float*)d_in[9];
    const float* Wr3 = (const float*)d_in[10];
    const float* Wout = (const float*)d_in[11];
    const float* bout = (const float*)d_in[12];
    float* out = (float*)d_out;

    const int N = in_sizes[0] / HD;       // 50000
    const int E = in_sizes[1] / 2;        // 800000
    const int NB = (N + BNODES - 1) >> BSH;   // 782 buckets
    const int n64 = N * HD;

    // Workspace layout — float4-accessed buffers first (16B alignment).
    _Float16* h16a = (_Float16*)d_ws;                // [N*64] f16
    _Float16* h16b = h16a + (size_t)N * HD;          // [N*64] f16
    int* ebuf     = (int*)(h16b + (size_t)N * HD);   // [NB*SLOT] packed edges
    int* colidx   = ebuf + (size_t)NB * SLOT;        // [NB*SLOT] padded CSR
    int* rowptr   = colidx + (size_t)NB * SLOT;      // [N]
    int* rowend   = rowptr + N;                      // [N]
    float* invdeg = (float*)(rowend + N);            // [N]
    int* bcur     = (int*)(invdeg + N);              // [784]

    hipMemsetAsync(bcur, 0, 784 * sizeof(int), stream);

    part_kernel<<<(E + CHUNK - 1) / CHUNK, 256, 0, stream>>>(ei, bcur, ebuf, E, NB);
    bsort_kernel<<<NB, 256, 0, stream>>>(ebuf, bcur, colidx, rowptr, rowend,
                                         invdeg, x, h16a, N, n64);

    const int ggrid = (N + 63) / 64;      // 782 tiles

    sage_fused<<<ggrid, 256, 0, stream>>>(h16a, h16b,
                                          rowptr, rowend, colidx, invdeg,
                                          Wl1, bl1, Wr1, N);
    sage_fused<<<ggrid, 256, 0, stream>>>(h16b, h16a,
                                          rowptr, rowend, colidx, invdeg,
                                          Wl2, bl2, Wr2, N);
    sage_fused_out<<<ggrid, 256, 0, stream>>>(h16a,
                                              rowptr, rowend, colidx, invdeg,
                                              Wl3, bl3, Wr3, Wout, bout, out, N);
}